// Round 1
// baseline (259.133 us; speedup 1.0000x reference)
//
#include <hip/hip_runtime.h>

// out[b, j, d] = exp(a[b, idx[j], d] * b[b, idx[j], d]
//                    + (a[b, idx[j], d] - b[b, idx[j], d]) * 0.5f) + 1.0f
// B=8, S=4096, D=1024, J=2048. Compute ONLY at gathered rows.
//
// One block per output row (B*J = 16384 rows), 256 threads/block,
// each thread handles one float4 (D = 1024 = 256 * 4).

#define B_DIM 8
#define S_DIM 4096
#define D_DIM 1024
#define J_DIM 2048

__global__ __launch_bounds__(256) void tree_fused_gather_kernel(
    const float* __restrict__ a,
    const float* __restrict__ b,
    const int* __restrict__ idx,
    float* __restrict__ out)
{
    const int row   = blockIdx.x;        // 0 .. B*J-1
    const int batch = row >> 11;         // row / J_DIM
    const int j     = row & (J_DIM - 1); // row % J_DIM

    const int s = idx[j];                // block-uniform -> scalar load

    const int src_off = (batch * S_DIM + s) * D_DIM + (threadIdx.x << 2);
    const int dst_off = row * D_DIM + (threadIdx.x << 2);

    const float4 av = *reinterpret_cast<const float4*>(a + src_off);
    const float4 bv = *reinterpret_cast<const float4*>(b + src_off);

    float4 o;
    o.x = __expf(av.x * bv.x + (av.x - bv.x) * 0.5f) + 1.0f;
    o.y = __expf(av.y * bv.y + (av.y - bv.y) * 0.5f) + 1.0f;
    o.z = __expf(av.z * bv.z + (av.z - bv.z) * 0.5f) + 1.0f;
    o.w = __expf(av.w * bv.w + (av.w - bv.w) * 0.5f) + 1.0f;

    *reinterpret_cast<float4*>(out + dst_off) = o;
}

extern "C" void kernel_launch(void* const* d_in, const int* in_sizes, int n_in,
                              void* d_out, int out_size, void* d_ws, size_t ws_size,
                              hipStream_t stream) {
    const float* a   = (const float*)d_in[0];
    const float* b   = (const float*)d_in[1];
    const int*   idx = (const int*)d_in[2];
    float* out = (float*)d_out;

    const int rows = B_DIM * J_DIM;      // 16384 blocks
    tree_fused_gather_kernel<<<rows, 256, 0, stream>>>(a, b, idx, out);
}